// Round 6
// baseline (307.698 us; speedup 1.0000x reference)
//
#include <hip/hip_runtime.h>
#include <math.h>

typedef float f32x4 __attribute__((ext_vector_type(4)));
typedef short short8 __attribute__((ext_vector_type(8)));

__device__ __forceinline__ short bf16r(float f) {
    union { float f; unsigned u; } x; x.f = f;
    unsigned u = x.u + 0x7fffu + ((x.u >> 16) & 1u);
    return (short)(u >> 16);
}

// ---------------------------------------------------------------------------
// pack_kernel: repack w2 (co,ci,j) fp32 -> B-fragment-ordered bf16 so that an
// MFMA B-frag (16x16x32: lane holds B[8*(lane>>4)+i][lane&15]) is one
// coalesced 16B/lane load: wpack[(((c*K+j)*2+kb)*64+lane)*8 + i]
//   element = w2[co = c*16+(lane&15)][ci = kb*32+8*((lane>>4)&3)+i][j]
// ---------------------------------------------------------------------------
template<int K>
__device__ __forceinline__ void pack_branch(const float* __restrict__ w2,
                                            short* __restrict__ wpack, int u) {
    int lane = u & 63;
    int kb   = (u >> 6) & 1;
    int rem  = u >> 7;          // c*K + j
    int j = rem % K, c = rem / K;
    int co  = c * 16 + (lane & 15);
    int cib = kb * 32 + 8 * ((lane >> 4) & 3);
    short8 v;
    #pragma unroll
    for (int i = 0; i < 8; ++i)
        v[i] = bf16r(w2[(co * 64 + (cib + i)) * K + j]);
    *reinterpret_cast<short8*>(wpack + (size_t)u * 8) = v;
}

__global__ __launch_bounds__(256) void pack_kernel(
    const float* __restrict__ w23, const float* __restrict__ w25,
    const float* __restrict__ w27,
    short* __restrict__ wp3, short* __restrict__ wp5, short* __restrict__ wp7)
{
    int tid = blockIdx.x * 256 + threadIdx.x;
    const int n3 = 8 * 3 * 2 * 64;   // 3072
    const int n5 = 8 * 5 * 2 * 64;   // 5120
    const int n7 = 8 * 7 * 2 * 64;   // 7168
    if (tid < n3)                pack_branch<3>(w23, wp3, tid);
    else if (tid < n3 + n5)      pack_branch<5>(w25, wp5, tid - n3);
    else if (tid < n3 + n5 + n7) pack_branch<7>(w27, wp7, tid - n3 - n5);
}

// ---------------------------------------------------------------------------
// branch_k<K>: one (bn) per block, 512 threads (8 waves), wave w owns c = w.
// Loop order: (j,kb) OUTER with ONE B-load per group; 13 independent
// accumulator chains inner (static acc[13], ds_read base + imm offsets —
// the XOR swizzle is lt-invariant since lt*16 % 8 == 0).
// __shared__ declared here -> true LDS addrspace (ds_read/ds_add).
// ---------------------------------------------------------------------------
template<int K>
__global__ __launch_bounds__(512) void branch_k(
    const float* __restrict__ x,      // (512, 200)
    const float* __restrict__ xmask,  // (512,)
    const float* __restrict__ w1,     // (64, K)
    const float* __restrict__ b1,     // (64,)
    const float* __restrict__ b2,     // (128,)
    const short* __restrict__ wpack,  // packed bf16 B
    float* __restrict__ pooled_g,     // (512, 3840)
    int br)
{
    constexpr int PAD = (K - 1) / 2;
    __shared__ float xs[208];
    __shared__ short t1s[232 * 64];      // [row = l+3][ci], XOR-swizzled rows
    __shared__ float pooled_s[128 * 12]; // [co][bin], pad 12
    __shared__ float b2s[128];

    const int bn   = blockIdx.x;
    const int t    = threadIdx.x;
    const int lane = t & 63;
    const int w    = t >> 6;            // 0..7
    const int lane15 = lane & 15;
    const int g      = (lane >> 4) & 3;

    if (xmask[bn] == 0.0f) return;      // xfc multiplies row by 0 -> exact

    // ---- P0: zero halos/pooled, preload b2 ----
    if (t < 208) xs[t] = 0.0f;
    for (int idx = t; idx < 32 * 64; idx += 512) {  // halo rows 0..2, 203..231
        int rr = idx >> 6;
        int row = (rr < 3) ? rr : (200 + rr);
        t1s[row * 64 + (idx & 63)] = 0;
    }
    for (int idx = t; idx < 128 * 12; idx += 512) pooled_s[idx] = 0.0f;
    if (t < 128) b2s[t] = b2[t];
    __syncthreads();

    if (t < 200) xs[3 + t] = x[bn * 200 + t];
    __syncthreads();

    // ---- P1: conv1 (ci = lane, l strided by wave), bf16 swizzled write ----
    {
        float w1_0 = w1[lane * K + 0], w1_1 = w1[lane * K + 1], w1_2 = w1[lane * K + 2];
        float w1_3 = 0.f, w1_4 = 0.f, w1_5 = 0.f, w1_6 = 0.f;
        if (K > 3) { w1_3 = w1[lane * K + 3]; w1_4 = w1[lane * K + 4]; }
        if (K > 5) { w1_5 = w1[lane * K + 5]; w1_6 = w1[lane * K + 6]; }
        const float b1r = b1[lane];
        for (int l = w; l < 200; l += 8) {
            const float* xp = &xs[3 + l - PAD];
            float a = b1r;
            a = fmaf(w1_0, xp[0], a);
            a = fmaf(w1_1, xp[1], a);
            a = fmaf(w1_2, xp[2], a);
            if (K > 3) { a = fmaf(w1_3, xp[3], a); a = fmaf(w1_4, xp[4], a); }
            if (K > 5) { a = fmaf(w1_5, xp[5], a); a = fmaf(w1_6, xp[6], a); }
            const int row = l + 3;
            t1s[row * 64 + (lane ^ ((row & 7) << 3))] = bf16r(fmaxf(a, 0.0f));
        }
    }
    __syncthreads();

    // ---- P2: MFMA. Wave w owns c = w; 13 chains per (j,kb) group. ----
    {
        const int c  = w;
        const int co = c * 16 + lane15;
        const float bb = b2s[co];
        const short* wpB = wpack + ((size_t)(c * 2 * K) * 64 + lane) * 8;

        f32x4 acc[13];
        #pragma unroll
        for (int lt = 0; lt < 13; ++lt) {
            f32x4 z = {0.f, 0.f, 0.f, 0.f};
            acc[lt] = z;
        }

        #pragma unroll
        for (int j = 0; j < K; ++j) {
            #pragma unroll
            for (int kb = 0; kb < 2; ++kb) {
                const short8 bfr = *reinterpret_cast<const short8*>(
                    wpB + (size_t)(j * 2 + kb) * 64 * 8);
                const int r0  = lane15 + 3 + j - PAD;            // row for lt=0
                const int col = (kb * 32 + 8 * g) ^ ((r0 & 7) << 3); // lt-invariant
                const short* abase = &t1s[r0 * 64 + col];
                #pragma unroll
                for (int lt = 0; lt < 13; ++lt) {
                    acc[lt] = __builtin_amdgcn_mfma_f32_16x16x32_bf16(
                        *reinterpret_cast<const short8*>(abase + lt * 1024),
                        bfr, acc[lt], 0, 0, 0);
                }
            }
        }

        // epilogue: C/D col = lane15 (co), row = 4g + r4 (l within tile)
        #pragma unroll
        for (int lt = 0; lt < 13; ++lt) {
            #pragma unroll
            for (int r4 = 0; r4 < 4; ++r4) {
                const int l = lt * 16 + 4 * g + r4;
                const float v = fmaxf(acc[lt][r4] + bb, 0.0f);
                if (lt < 12 || l < 200)
                    atomicAdd(&pooled_s[co * 12 + l / 20], v);
            }
        }
    }
    __syncthreads();

    // ---- P3: store pooled row (mean = sum/20) ----
    for (int idx = t; idx < 1280; idx += 512) {
        int co2 = idx / 10, bin = idx - co2 * 10;
        pooled_g[bn * 3840 + br * 1280 + idx] = pooled_s[co2 * 12 + bin] * 0.05f;
    }
}

// ---------------------------------------------------------------------------
// xfc: xfeat(512,32) = (pooled @ w_xfc.T + b_xfc) * valid   (round-1 proven)
// ---------------------------------------------------------------------------
__global__ __launch_bounds__(256) void xfc_kernel(
    const float* __restrict__ pooled,   // (512, 3840)
    const float* __restrict__ w_xfc,    // (32, 3840)
    const float* __restrict__ b_xfc,    // (32,)
    const float* __restrict__ xmask,    // (512,)
    float* __restrict__ xfeat)          // (512, 32)
{
    const int bn = blockIdx.x;
    const int t  = threadIdx.x;
    __shared__ float prow[3840];
    const float* pr = pooled + bn * 3840;
    for (int i = t; i < 3840; i += 256) prow[i] = pr[i];
    __syncthreads();

    const int o = t >> 3, part = t & 7;   // 8 threads per output
    const float* wr = w_xfc + o * 3840;
    float a = 0.0f;
    for (int i = part; i < 3840; i += 8)
        a = fmaf(prow[i], wr[i], a);
    a += __shfl_xor(a, 1);
    a += __shfl_xor(a, 2);
    a += __shfl_xor(a, 4);
    if (part == 0) xfeat[bn * 32 + o] = (a + b_xfc[o]) * xmask[bn];
}

// ---------------------------------------------------------------------------
// Tail: elements processor + fuse + 4-head attention + pool + regressor.
// One block per batch b (32 blocks).
// ---------------------------------------------------------------------------
__global__ __launch_bounds__(256) void tail_kernel(
    const float* __restrict__ xfeat,      // (512, 32)
    const float* __restrict__ elem_info,  // (32, 16, 7)
    const float* __restrict__ emaskp,     // (32, 16)
    const float* __restrict__ w_float, const float* __restrict__ b_float,
    const float* __restrict__ atom_emb, const float* __restrict__ type_emb,
    const float* __restrict__ w_fuse,  const float* __restrict__ b_fuse,
    const float* __restrict__ in_w,    const float* __restrict__ in_b,
    const float* __restrict__ out_w,   const float* __restrict__ out_b,
    const float* __restrict__ w_fc1,   const float* __restrict__ b_fc1,
    const float* __restrict__ w_fc2,   const float* __restrict__ b_fc2,
    float* __restrict__ out)              // (32,)
{
    const int b = blockIdx.x;
    const int t = threadIdx.x;

    __shared__ float fu[16][60];
    __shared__ float fused[16][64];
    __shared__ float qkvs[16][192];
    __shared__ float sc[4][16][16];
    __shared__ float ao[16][64];
    __shared__ float aoo[16][64];
    __shared__ float p2s[64];
    __shared__ float hs[64];
    __shared__ float em[16];

    if (t < 16) em[t] = emaskp[b * 16 + t];
    for (int d = t; d < 512; d += 256) {
        int n = d >> 5, o = d & 31;
        fu[n][o] = xfeat[(b * 16 + n) * 32 + o];
    }
    __syncthreads();

    {
        int n = t >> 4, slot = t & 15;
        float m  = em[n];
        float vE = (m >= 0.5f) ? 1.0f : 0.0f;
        const float* ei = elem_info + (b * 16 + n) * 7;
        float a = b_float[slot];
        #pragma unroll
        for (int i = 0; i < 5; ++i)
            a = fmaf(ei[i] * m, w_float[slot * 5 + i], a);
        fu[n][32 + slot] = fmaxf(a, 0.0f) * vE * m;

        int an = (int)(ei[5] * m);
        int et = (int)(ei[6] * m);
        float take = (vE != 0.0f && an >= 1 && an <= 94) ? 1.0f : 0.0f;
        int anc = an < 0 ? 0 : (an > 94 ? 94 : an);
        int etc = et < 0 ? 0 : (et > 5 ? 5 : et);
        if (slot < 8)
            fu[n][48 + slot] = atom_emb[anc * 8 + slot] * take * m;
        else if (slot < 12)
            fu[n][56 + (slot - 8)] = type_emb[etc * 4 + (slot - 8)] * take * m;
    }
    __syncthreads();

    for (int d = t; d < 1024; d += 256) {
        int n = d >> 6, o = d & 63;
        float a = b_fuse[o];
        const float* wr = w_fuse + o * 60;
        #pragma unroll
        for (int i = 0; i < 60; ++i) a = fmaf(fu[n][i], wr[i], a);
        fused[n][o] = a * em[n];
    }
    __syncthreads();

    for (int d = t; d < 3072; d += 256) {
        int n = d / 192, rr = d - n * 192;
        float a = in_b[rr];
        const float* wr = in_w + rr * 64;
        #pragma unroll
        for (int i = 0; i < 64; ++i) a = fmaf(fused[n][i], wr[i], a);
        qkvs[n][rr] = a;
    }
    __syncthreads();

    for (int d = t; d < 1024; d += 256) {
        int h = d >> 8, i = (d >> 4) & 15, j = d & 15;
        float a = 0.0f;
        #pragma unroll
        for (int dd = 0; dd < 16; ++dd)
            a = fmaf(qkvs[i][h * 16 + dd], qkvs[j][64 + h * 16 + dd], a);
        a *= 0.25f;
        if (em[j] < 0.5f) a = -1e30f;
        sc[h][i][j] = a;
    }
    __syncthreads();

    if (t < 64) {
        int h = t >> 4, i = t & 15;
        float mx = -3.4e38f;
        #pragma unroll
        for (int j = 0; j < 16; ++j) mx = fmaxf(mx, sc[h][i][j]);
        float e[16];
        float s = 0.0f;
        #pragma unroll
        for (int j = 0; j < 16; ++j) { e[j] = expf(sc[h][i][j] - mx); s += e[j]; }
        float inv = 1.0f / s;
        #pragma unroll
        for (int j = 0; j < 16; ++j) sc[h][i][j] = e[j] * inv;
    }
    __syncthreads();

    for (int d = t; d < 1024; d += 256) {
        int n = d >> 6, e = d & 63, h = e >> 4;
        float a = 0.0f;
        #pragma unroll
        for (int j = 0; j < 16; ++j)
            a = fmaf(sc[h][n][j], qkvs[j][128 + e], a);
        ao[n][e] = a;
    }
    __syncthreads();

    for (int d = t; d < 1024; d += 256) {
        int n = d >> 6, o = d & 63;
        float a = out_b[o];
        const float* wr = out_w + o * 64;
        #pragma unroll
        for (int i = 0; i < 64; ++i) a = fmaf(ao[n][i], wr[i], a);
        aoo[n][o] = a * em[n];
    }
    __syncthreads();

    if (t < 64) {
        float s = 0.0f, ms = 0.0f;
        #pragma unroll
        for (int n = 0; n < 16; ++n) { s += aoo[n][t]; ms += em[n]; }
        p2s[t] = s / (ms + 1e-8f);
    }
    __syncthreads();

    if (t < 64) {
        float a = b_fc1[t];
        const float* wr = w_fc1 + t * 64;
        #pragma unroll
        for (int i = 0; i < 64; ++i) a = fmaf(p2s[i], wr[i], a);
        hs[t] = fmaxf(a, 0.0f);
    }
    __syncthreads();

    if (t < 64) {
        float v = hs[t] * w_fc2[t];
        #pragma unroll
        for (int d2 = 32; d2 >= 1; d2 >>= 1) v += __shfl_xor(v, d2);
        if (t == 0) out[b] = v + b_fc2[0];
    }
}

extern "C" void kernel_launch(void* const* d_in, const int* in_sizes, int n_in,
                              void* d_out, int out_size, void* d_ws, size_t ws_size,
                              hipStream_t stream)
{
    (void)in_sizes; (void)n_in; (void)out_size; (void)ws_size;
    const float* x     = (const float*)d_in[0];
    const float* xmask = (const float*)d_in[1];
    const float* einfo = (const float*)d_in[2];
    const float* emask = (const float*)d_in[3];

    float* pooled = (float*)d_ws;                 // 512*3840 f32 = 7.86 MB
    float* xfeat  = pooled + 512 * 3840;          // 512*32 f32
    short* wp3 = (short*)(xfeat + 512 * 32);      // 3072*8 shorts
    short* wp5 = wp3 + 24576;                     // 5120*8 shorts
    short* wp7 = wp5 + 40960;                     // 7168*8 shorts

    pack_kernel<<<60, 256, 0, stream>>>(
        (const float*)d_in[6], (const float*)d_in[10], (const float*)d_in[14],
        wp3, wp5, wp7);

    branch_k<3><<<512, 512, 0, stream>>>(x, xmask,
        (const float*)d_in[4],  (const float*)d_in[5],  (const float*)d_in[7],
        wp3, pooled, 0);
    branch_k<5><<<512, 512, 0, stream>>>(x, xmask,
        (const float*)d_in[8],  (const float*)d_in[9],  (const float*)d_in[11],
        wp5, pooled, 1);
    branch_k<7><<<512, 512, 0, stream>>>(x, xmask,
        (const float*)d_in[12], (const float*)d_in[13], (const float*)d_in[15],
        wp7, pooled, 2);

    xfc_kernel<<<512, 256, 0, stream>>>(pooled,
        (const float*)d_in[16], (const float*)d_in[17], xmask, xfeat);

    tail_kernel<<<32, 256, 0, stream>>>(xfeat, einfo, emask,
        (const float*)d_in[18], (const float*)d_in[19],
        (const float*)d_in[20], (const float*)d_in[21],
        (const float*)d_in[22], (const float*)d_in[23],
        (const float*)d_in[24], (const float*)d_in[25],
        (const float*)d_in[26], (const float*)d_in[27],
        (const float*)d_in[28], (const float*)d_in[29],
        (const float*)d_in[30], (const float*)d_in[31],
        (float*)d_out);
}

// Round 7
// 83.185 us; speedup vs baseline: 3.6989x; 3.6989x over previous
//
#include <hip/hip_runtime.h>
#include <math.h>

typedef float f32x4 __attribute__((ext_vector_type(4)));
typedef short short8 __attribute__((ext_vector_type(8)));

__device__ __forceinline__ short bf16r(float f) {
    union { float f; unsigned u; } x; x.f = f;
    unsigned u = x.u + 0x7fffu + ((x.u >> 16) & 1u);
    return (short)(u >> 16);
}

// ---------------------------------------------------------------------------
// pack_kernel: repack w2 (co,ci,j) fp32 -> B-fragment-ordered bf16 so that an
// MFMA B-frag (16x16x32: lane holds B[8*(lane>>4)+i][lane&15]) is one
// coalesced 16B/lane load: wpack[(((c*K+j)*2+kb)*64+lane)*8 + i]
// ---------------------------------------------------------------------------
template<int K>
__device__ __forceinline__ void pack_branch(const float* __restrict__ w2,
                                            short* __restrict__ wpack, int u) {
    int lane = u & 63;
    int kb   = (u >> 6) & 1;
    int rem  = u >> 7;          // c*K + j
    int j = rem % K, c = rem / K;
    int co  = c * 16 + (lane & 15);
    int cib = kb * 32 + 8 * ((lane >> 4) & 3);
    short8 v;
    #pragma unroll
    for (int i = 0; i < 8; ++i)
        v[i] = bf16r(w2[(co * 64 + (cib + i)) * K + j]);
    *reinterpret_cast<short8*>(wpack + (size_t)u * 8) = v;
}

__global__ __launch_bounds__(256) void pack_kernel(
    const float* __restrict__ w23, const float* __restrict__ w25,
    const float* __restrict__ w27,
    short* __restrict__ wp3, short* __restrict__ wp5, short* __restrict__ wp7)
{
    int tid = blockIdx.x * 256 + threadIdx.x;
    const int n3 = 8 * 3 * 2 * 64;   // 3072
    const int n5 = 8 * 5 * 2 * 64;   // 5120
    const int n7 = 8 * 7 * 2 * 64;   // 7168
    if (tid < n3)                pack_branch<3>(w23, wp3, tid);
    else if (tid < n3 + n5)      pack_branch<5>(w25, wp5, tid - n3);
    else if (tid < n3 + n5 + n7) pack_branch<7>(w27, wp7, tid - n3 - n5);
}

// ---------------------------------------------------------------------------
// pool_accum<GV>: add this thread's relu'd accumulator elements into the
// 10 pool bins. GV = g (lane>>4) is a template arg so l and l/20 are
// compile-time -> pb[] is statically indexed (registers, no scratch).
// ---------------------------------------------------------------------------
template<int GV>
__device__ __forceinline__ void pool_accum(const f32x4* acc, float bb, float* pb) {
    #pragma unroll
    for (int lt = 0; lt < 13; ++lt) {
        #pragma unroll
        for (int r4 = 0; r4 < 4; ++r4) {
            const int l = lt * 16 + 4 * GV + r4;   // compile-time
            if (l < 200)
                pb[l / 20] += fmaxf(acc[lt][r4] + bb, 0.0f);
        }
    }
}

// ---------------------------------------------------------------------------
// branch_body<K>: one (bn) for one branch. 512 threads, wave w owns c = w.
//   conv1 (VALU) -> t1s[l+3][ci] bf16 XOR-swizzled; conv2 = MFMA 16x16x32
//   with (j,kb) outer (1 B-load per group) and 13 independent acc chains;
//   epilogue: per-thread register pooling + shfl_xor(16/32) reduce + ONE
//   plain LDS store per (co,bin) — zero atomics (the round-6 81us cost).
// ---------------------------------------------------------------------------
template<int K>
__device__ __forceinline__ void branch_body(
    const int bn, const int t,
    const float* __restrict__ x, const float* __restrict__ xmask,
    const float* __restrict__ w1, const float* __restrict__ b1,
    const float* __restrict__ b2, const short* __restrict__ wpack,
    float* __restrict__ pooled_g, int br,
    float* xs, short* t1s, float* pooled_s, float* b2s)
{
    constexpr int PAD = (K - 1) / 2;
    const int lane = t & 63;
    const int w    = t >> 6;            // 0..7
    const int lane15 = lane & 15;
    const int g      = (lane >> 4) & 3;

    if (xmask[bn] == 0.0f) return;      // xfc multiplies row by 0 -> exact

    // ---- P0: zero halos, preload b2 ----
    if (t < 208) xs[t] = 0.0f;
    for (int idx = t; idx < 32 * 64; idx += 512) {  // halo rows 0..2, 203..231
        int rr = idx >> 6;
        int row = (rr < 3) ? rr : (200 + rr);
        t1s[row * 64 + (idx & 63)] = 0;
    }
    if (t < 128) b2s[t] = b2[t];
    __syncthreads();

    if (t < 200) xs[3 + t] = x[bn * 200 + t];
    __syncthreads();

    // ---- P1: conv1 (ci = lane, l strided by wave), bf16 swizzled write ----
    {
        float w1_0 = w1[lane * K + 0], w1_1 = w1[lane * K + 1], w1_2 = w1[lane * K + 2];
        float w1_3 = 0.f, w1_4 = 0.f, w1_5 = 0.f, w1_6 = 0.f;
        if (K > 3) { w1_3 = w1[lane * K + 3]; w1_4 = w1[lane * K + 4]; }
        if (K > 5) { w1_5 = w1[lane * K + 5]; w1_6 = w1[lane * K + 6]; }
        const float b1r = b1[lane];
        for (int l = w; l < 200; l += 8) {
            const float* xp = &xs[3 + l - PAD];
            float a = b1r;
            a = fmaf(w1_0, xp[0], a);
            a = fmaf(w1_1, xp[1], a);
            a = fmaf(w1_2, xp[2], a);
            if (K > 3) { a = fmaf(w1_3, xp[3], a); a = fmaf(w1_4, xp[4], a); }
            if (K > 5) { a = fmaf(w1_5, xp[5], a); a = fmaf(w1_6, xp[6], a); }
            const int row = l + 3;
            t1s[row * 64 + (lane ^ ((row & 7) << 3))] = bf16r(fmaxf(a, 0.0f));
        }
    }
    __syncthreads();

    // ---- P2: MFMA. Wave w owns c = w; 13 chains per (j,kb) group. ----
    const int co = w * 16 + lane15;
    const float bb = b2s[co];
    f32x4 acc[13];
    #pragma unroll
    for (int lt = 0; lt < 13; ++lt) {
        f32x4 z = {0.f, 0.f, 0.f, 0.f};
        acc[lt] = z;
    }
    {
        const short* wpB = wpack + ((size_t)(w * 2 * K) * 64 + lane) * 8;
        #pragma unroll
        for (int j = 0; j < K; ++j) {
            #pragma unroll
            for (int kb = 0; kb < 2; ++kb) {
                const short8 bfr = *reinterpret_cast<const short8*>(
                    wpB + (size_t)(j * 2 + kb) * 64 * 8);
                const int r0  = lane15 + 3 + j - PAD;                // row for lt=0
                const int col = (kb * 32 + 8 * g) ^ ((r0 & 7) << 3); // lt-invariant
                const short* abase = &t1s[r0 * 64 + col];
                #pragma unroll
                for (int lt = 0; lt < 13; ++lt) {
                    acc[lt] = __builtin_amdgcn_mfma_f32_16x16x32_bf16(
                        *reinterpret_cast<const short8*>(abase + lt * 1024),
                        bfr, acc[lt], 0, 0, 0);
                }
            }
        }
    }

    // ---- P3: atomic-free pooling epilogue ----
    {
        float pb[10];
        #pragma unroll
        for (int b = 0; b < 10; ++b) pb[b] = 0.0f;
        if      (g == 0) pool_accum<0>(acc, bb, pb);
        else if (g == 1) pool_accum<1>(acc, bb, pb);
        else if (g == 2) pool_accum<2>(acc, bb, pb);
        else             pool_accum<3>(acc, bb, pb);
        // reduce the 4 co-sharing lanes (lane ^ 16, ^ 32)
        #pragma unroll
        for (int b = 0; b < 10; ++b) {
            pb[b] += __shfl_xor(pb[b], 16);
            pb[b] += __shfl_xor(pb[b], 32);
        }
        if (lane < 16) {
            #pragma unroll
            for (int b = 0; b < 10; ++b)
                pooled_s[co * 12 + b] = pb[b];
        }
    }
    __syncthreads();

    // ---- P4: store pooled row (mean = sum/20) ----
    for (int idx = t; idx < 1280; idx += 512) {
        int co2 = idx / 10, bin = idx - co2 * 10;
        pooled_g[bn * 3840 + br * 1280 + idx] = pooled_s[co2 * 12 + bin] * 0.05f;
    }
}

__global__ __launch_bounds__(512) void branch_fused(
    const float* __restrict__ x, const float* __restrict__ xmask,
    const float* __restrict__ w1_3, const float* __restrict__ b1_3,
    const float* __restrict__ b2_3, const short* __restrict__ wp3,
    const float* __restrict__ w1_5, const float* __restrict__ b1_5,
    const float* __restrict__ b2_5, const short* __restrict__ wp5,
    const float* __restrict__ w1_7, const float* __restrict__ b1_7,
    const float* __restrict__ b2_7, const short* __restrict__ wp7,
    float* __restrict__ pooled_g)
{
    __shared__ float xs[208];
    __shared__ short t1s[232 * 64];
    __shared__ float pooled_s[128 * 12];
    __shared__ float b2s[128];

    const int bn = blockIdx.x;
    const int br = blockIdx.y;
    const int t  = threadIdx.x;

    if (br == 0)
        branch_body<3>(bn, t, x, xmask, w1_3, b1_3, b2_3, wp3, pooled_g, 0,
                       xs, t1s, pooled_s, b2s);
    else if (br == 1)
        branch_body<5>(bn, t, x, xmask, w1_5, b1_5, b2_5, wp5, pooled_g, 1,
                       xs, t1s, pooled_s, b2s);
    else
        branch_body<7>(bn, t, x, xmask, w1_7, b1_7, b2_7, wp7, pooled_g, 2,
                       xs, t1s, pooled_s, b2s);
}

// ---------------------------------------------------------------------------
// xfc: xfeat(512,32) = (pooled @ w_xfc.T + b_xfc) * valid.
// Wave ww owns outputs ww*8..ww*8+7. Per output: 15 static-unrolled float4
// iterations, coalesced 1KB/wave w_xfc loads, dual accumulator chains,
// then a 6-step shfl_xor reduce. Fixes the round-6 VGPR=8 serial loop.
// ---------------------------------------------------------------------------
__global__ __launch_bounds__(256) void xfc_kernel(
    const float* __restrict__ pooled,   // (512, 3840)
    const float* __restrict__ w_xfc,    // (32, 3840)
    const float* __restrict__ b_xfc,    // (32,)
    const float* __restrict__ xmask,    // (512,)
    float* __restrict__ xfeat)          // (512, 32)
{
    const int bn   = blockIdx.x;
    const int t    = threadIdx.x;
    const int lane = t & 63;
    const int ww   = t >> 6;
    __shared__ f32x4 prow4[960];
    const f32x4* pr4 = reinterpret_cast<const f32x4*>(pooled + bn * 3840);
    for (int i = t; i < 960; i += 256) prow4[i] = pr4[i];
    __syncthreads();

    const float m = xmask[bn];
    #pragma unroll
    for (int k = 0; k < 8; ++k) {
        const int o = ww * 8 + k;
        const f32x4* wr4 = reinterpret_cast<const f32x4*>(w_xfc + o * 3840) + lane;
        float a0 = 0.0f, a1 = 0.0f;
        #pragma unroll
        for (int it = 0; it < 15; ++it) {
            const f32x4 wv = wr4[it * 64];
            const f32x4 pv = prow4[it * 64 + lane];
            float s = wv[0] * pv[0];
            s = fmaf(wv[1], pv[1], s);
            s = fmaf(wv[2], pv[2], s);
            s = fmaf(wv[3], pv[3], s);
            if (it & 1) a1 += s; else a0 += s;
        }
        float a = a0 + a1;
        #pragma unroll
        for (int d = 32; d >= 1; d >>= 1) a += __shfl_xor(a, d);
        if (lane == 0) xfeat[bn * 32 + o] = (a + b_xfc[o]) * m;
    }
}

// ---------------------------------------------------------------------------
// Tail: elements processor + fuse + 4-head attention + pool + regressor.
// One block per batch b (32 blocks).
// ---------------------------------------------------------------------------
__global__ __launch_bounds__(256) void tail_kernel(
    const float* __restrict__ xfeat,      // (512, 32)
    const float* __restrict__ elem_info,  // (32, 16, 7)
    const float* __restrict__ emaskp,     // (32, 16)
    const float* __restrict__ w_float, const float* __restrict__ b_float,
    const float* __restrict__ atom_emb, const float* __restrict__ type_emb,
    const float* __restrict__ w_fuse,  const float* __restrict__ b_fuse,
    const float* __restrict__ in_w,    const float* __restrict__ in_b,
    const float* __restrict__ out_w,   const float* __restrict__ out_b,
    const float* __restrict__ w_fc1,   const float* __restrict__ b_fc1,
    const float* __restrict__ w_fc2,   const float* __restrict__ b_fc2,
    float* __restrict__ out)              // (32,)
{
    const int b = blockIdx.x;
    const int t = threadIdx.x;

    __shared__ float fu[16][60];
    __shared__ float fused[16][64];
    __shared__ float qkvs[16][192];
    __shared__ float sc[4][16][16];
    __shared__ float ao[16][64];
    __shared__ float aoo[16][64];
    __shared__ float p2s[64];
    __shared__ float hs[64];
    __shared__ float em[16];

    if (t < 16) em[t] = emaskp[b * 16 + t];
    for (int d = t; d < 512; d += 256) {
        int n = d >> 5, o = d & 31;
        fu[n][o] = xfeat[(b * 16 + n) * 32 + o];
    }
    __syncthreads();

    {
        int n = t >> 4, slot = t & 15;
        float m  = em[n];
        float vE = (m >= 0.5f) ? 1.0f : 0.0f;
        const float* ei = elem_info + (b * 16 + n) * 7;
        float a = b_float[slot];
        #pragma unroll
        for (int i = 0; i < 5; ++i)
            a = fmaf(ei[i] * m, w_float[slot * 5 + i], a);
        fu[n][32 + slot] = fmaxf(a, 0.0f) * vE * m;

        int an = (int)(ei[5] * m);
        int et = (int)(ei[6] * m);
        float take = (vE != 0.0f && an >= 1 && an <= 94) ? 1.0f : 0.0f;
        int anc = an < 0 ? 0 : (an > 94 ? 94 : an);
        int etc = et < 0 ? 0 : (et > 5 ? 5 : et);
        if (slot < 8)
            fu[n][48 + slot] = atom_emb[anc * 8 + slot] * take * m;
        else if (slot < 12)
            fu[n][56 + (slot - 8)] = type_emb[etc * 4 + (slot - 8)] * take * m;
    }
    __syncthreads();

    for (int d = t; d < 1024; d += 256) {
        int n = d >> 6, o = d & 63;
        float a = b_fuse[o];
        const float* wr = w_fuse + o * 60;
        #pragma unroll
        for (int i = 0; i < 60; ++i) a = fmaf(fu[n][i], wr[i], a);
        fused[n][o] = a * em[n];
    }
    __syncthreads();

    for (int d = t; d < 3072; d += 256) {
        int n = d / 192, rr = d - n * 192;
        float a = in_b[rr];
        const float* wr = in_w + rr * 64;
        #pragma unroll
        for (int i = 0; i < 64; ++i) a = fmaf(fused[n][i], wr[i], a);
        qkvs[n][rr] = a;
    }
    __syncthreads();

    for (int d = t; d < 1024; d += 256) {
        int h = d >> 8, i = (d >> 4) & 15, j = d & 15;
        float a = 0.0f;
        #pragma unroll
        for (int dd = 0; dd < 16; ++dd)
            a = fmaf(qkvs[i][h * 16 + dd], qkvs[j][64 + h * 16 + dd], a);
        a *= 0.25f;
        if (em[j] < 0.5f) a = -1e30f;
        sc[h][i][j] = a;
    }
    __syncthreads();

    if (t < 64) {
        int h = t >> 4, i = t & 15;
        float mx = -3.4e38f;
        #pragma unroll
        for (int j = 0; j < 16; ++j) mx = fmaxf(mx, sc[h][i][j]);
        float e[16];
        float s = 0.0f;
        #pragma unroll
        for (int j = 0; j < 16; ++j) { e[j] = expf(sc[h][i][j] - mx); s += e[j]; }
        float inv = 1.0f / s;
        #pragma unroll
        for (int j = 0; j < 16; ++j) sc[h][i][j] = e[j] * inv;
    }
    __syncthreads();

    for (int d = t; d < 1024; d += 256) {
        int n = d >> 6, e = d & 63, h = e >> 4;
        float a = 0.0f;
        #pragma unroll
        for (int j = 0; j < 16; ++j)
            a = fmaf(sc[h][n][j], qkvs[j][128 + e], a);
        ao[n][e] = a;
    }
    __syncthreads();

    for (int d = t; d < 1024; d += 256) {
        int n = d >> 6, o = d & 63;
        float a = out_b[o];
        const float* wr = out_w + o * 64;
        #pragma unroll
        for (int i = 0; i < 64; ++i) a = fmaf(ao[n][i], wr[i], a);
        aoo[n][o] = a * em[n];
    }
    __syncthreads();

    if (t < 64) {
        float s = 0.0f, ms = 0.0f;
        #pragma unroll
        for (int n = 0; n < 16; ++n) { s += aoo[n][t]; ms += em[n]; }
        p2s[t] = s / (ms + 1e-8f);
    }
    __syncthreads();

    if (t < 64) {
        float a = b_fc1[t];
        const float* wr = w_fc1 + t * 64;
        #pragma unroll
        for (int i = 0; i < 64; ++i) a = fmaf(p2s[i], wr[i], a);
        hs[t] = fmaxf(a, 0.0f);
    }
    __syncthreads();

    if (t < 64) {
        float v = hs[t] * w_fc2[t];
        #pragma unroll
        for (int d2 = 32; d2 >= 1; d2 >>= 1) v += __shfl_xor(v, d2);
        if (t == 0) out[b] = v + b_fc2[0];
    }
}

extern "C" void kernel_launch(void* const* d_in, const int* in_sizes, int n_in,
                              void* d_out, int out_size, void* d_ws, size_t ws_size,
                              hipStream_t stream)
{
    (void)in_sizes; (void)n_in; (void)out_size; (void)ws_size;
    const float* x     = (const float*)d_in[0];
    const float* xmask = (const float*)d_in[1];
    const float* einfo = (const float*)d_in[2];
    const float* emask = (const float*)d_in[3];

    float* pooled = (float*)d_ws;                 // 512*3840 f32 = 7.86 MB
    float* xfeat  = pooled + 512 * 3840;          // 512*32 f32
    short* wp3 = (short*)(xfeat + 512 * 32);      // 3072*8 shorts
    short* wp5 = wp3 + 24576;                     // 5120*8 shorts
    short* wp7 = wp5 + 40960;                     // 7168*8 shorts

    pack_kernel<<<60, 256, 0, stream>>>(
        (const float*)d_in[6], (const float*)d_in[10], (const float*)d_in[14],
        wp3, wp5, wp7);

    branch_fused<<<dim3(512, 3), 512, 0, stream>>>(x, xmask,
        (const float*)d_in[4],  (const float*)d_in[5],  (const float*)d_in[7],  wp3,
        (const float*)d_in[8],  (const float*)d_in[9],  (const float*)d_in[11], wp5,
        (const float*)d_in[12], (const float*)d_in[13], (const float*)d_in[15], wp7,
        pooled);

    xfc_kernel<<<512, 256, 0, stream>>>(pooled,
        (const float*)d_in[16], (const float*)d_in[17], xmask, xfeat);

    tail_kernel<<<32, 256, 0, stream>>>(xfeat, einfo, emask,
        (const float*)d_in[18], (const float*)d_in[19],
        (const float*)d_in[20], (const float*)d_in[21],
        (const float*)d_in[22], (const float*)d_in[23],
        (const float*)d_in[24], (const float*)d_in[25],
        (const float*)d_in[26], (const float*)d_in[27],
        (const float*)d_in[28], (const float*)d_in[29],
        (const float*)d_in[30], (const float*)d_in[31],
        (float*)d_out);
}